// Round 1
// baseline (222.856 us; speedup 1.0000x reference)
//
#include <hip/hip_runtime.h>

// ---------------------------------------------------------------------------
// CrossAttention (self-attn): B=2 N=4096 D=512 H=8 DH=64
// Pipeline: cvt(x,W) -> GEMM qkv (bf16 mfma, V stored transposed) ->
//           flash attention (mfma 16x16x32, online softmax) -> GEMM out + bias
// Workspace layout (bytes):
//   Xb   @ 0         : 8192x512 bf16   (8,388,608)
//   WtQ/K/V/O @ 8388608 : 4 x 512x512 bf16 (N-major)  (2,097,152)
//   Q    @ 10485760  : (B,H,N,DH) bf16, pre-scaled by SCALE*log2(e)
//   K    @ 18874368  : (B,H,N,DH) bf16
//   Vt   @ 27262976  : (B,H,DH,N) bf16  (transposed for PV B-fragments)
//   O    @ 35651584  : (B,N,H*DH) bf16
// total 44,040,192 B
// ---------------------------------------------------------------------------

typedef __bf16 bf16;
typedef __bf16 bf16x2 __attribute__((ext_vector_type(2)));
typedef __bf16 bf16x4 __attribute__((ext_vector_type(4)));
typedef __bf16 bf16x8 __attribute__((ext_vector_type(8)));
typedef float  f32x4  __attribute__((ext_vector_type(4)));

#define MFMA16 __builtin_amdgcn_mfma_f32_16x16x32_bf16

// XOR swizzle for 128B-row LDS tiles: byte ^= ((row&7)<<4)
__device__ __forceinline__ int swz(int b) { return b ^ ((b >> 3) & 0x70); }

__device__ __forceinline__ void gload16(const void* g, void* l) {
  __builtin_amdgcn_global_load_lds(
      (const __attribute__((address_space(1))) unsigned int*)g,
      (__attribute__((address_space(3))) unsigned int*)l, 16, 0, 0);
}

// ---------------------------------------------------------------------------
__global__ __launch_bounds__(256) void k_cvt_x(const float* __restrict__ x,
                                               bf16* __restrict__ xb) {
  int i = (blockIdx.x * 256 + threadIdx.x) * 4;
  f32x4 v = *(const f32x4*)(x + i);
  bf16x4 o;
  o[0] = (bf16)v[0]; o[1] = (bf16)v[1]; o[2] = (bf16)v[2]; o[3] = (bf16)v[3];
  *(bf16x4*)(xb + i) = o;
}

__global__ __launch_bounds__(256) void k_cvt_w(const float* __restrict__ Wq,
                                               const float* __restrict__ Wk,
                                               const float* __restrict__ Wv,
                                               const float* __restrict__ Wo,
                                               bf16* __restrict__ Wts) {
  int t = blockIdx.x * 256 + threadIdx.x;       // 0 .. 4*512*512-1
  int w = t >> 18, idx = t & 262143;
  int k = idx >> 9, n = idx & 511;
  const float* W = (w == 0) ? Wq : (w == 1) ? Wk : (w == 2) ? Wv : Wo;
  Wts[(size_t)w * 262144 + n * 512 + k] = (bf16)W[k * 512 + n];
}

// ---------------------------------------------------------------------------
// 128x128 tile GEMM mainloop, K=512, BK=64, 4 waves (2x2 of 64x64)
__device__ __forceinline__ void gemm_mainloop(const char* Ag, const char* Bg,
                                              char* sA, char* sB, f32x4 acc[4][4]) {
  const int tid = threadIdx.x;
  const int g = (tid >> 4) & 3, lr = tid & 15;
  const int wr = ((tid >> 7) & 1) * 64, wc = ((tid >> 6) & 1) * 64;
  f32x4 zero = {0.f, 0.f, 0.f, 0.f};
#pragma unroll
  for (int mt = 0; mt < 4; mt++)
#pragma unroll
    for (int nt = 0; nt < 4; nt++) acc[mt][nt] = zero;

  for (int k0 = 0; k0 < 512; k0 += 64) {
#pragma unroll
    for (int i = 0; i < 4; i++) {  // A tile: 128 rows x 64 k (16KB)
      int c = i * 256 + tid;
      int row = c >> 3, cl = (c & 7) ^ (row & 7);   // pre-swizzled source chunk
      gload16(Ag + row * 1024 + k0 * 2 + cl * 16, sA + (c & ~63) * 16);
    }
#pragma unroll
    for (int i = 0; i < 4; i++) {  // B tile (N-major weights): 128 rows x 64 k
      int c = i * 256 + tid;
      int row = c >> 3, cl = (c & 7) ^ (row & 7);
      gload16(Bg + row * 1024 + k0 * 2 + cl * 16, sB + (c & ~63) * 16);
    }
    __syncthreads();
#pragma unroll
    for (int kk = 0; kk < 2; kk++) {
      bf16x8 af[4], bfr[4];
#pragma unroll
      for (int mt = 0; mt < 4; mt++)
        af[mt] = *(const bf16x8*)(sA + swz((wr + mt * 16 + lr) * 128 + kk * 64 + g * 16));
#pragma unroll
      for (int nt = 0; nt < 4; nt++)
        bfr[nt] = *(const bf16x8*)(sB + swz((wc + nt * 16 + lr) * 128 + kk * 64 + g * 16));
#pragma unroll
      for (int mt = 0; mt < 4; mt++)
#pragma unroll
        for (int nt = 0; nt < 4; nt++)
          acc[mt][nt] = MFMA16(af[mt], bfr[nt], acc[mt][nt], 0, 0, 0);
    }
    __syncthreads();
  }
}

// z = 0:Q (scaled), 1:K, 2:V (transposed store)
__global__ __launch_bounds__(256) void k_gemm_qkv(const bf16* __restrict__ Xb,
                                                  const bf16* __restrict__ Wts,
                                                  bf16* __restrict__ Qo,
                                                  bf16* __restrict__ Ko,
                                                  bf16* __restrict__ Vto) {
  __shared__ __align__(16) char smem[32768];
  const int tid = threadIdx.x;
  const int g = (tid >> 4) & 3, lr = tid & 15;
  const int mb = blockIdx.x * 128, nb = blockIdx.y * 128;
  const int mode = blockIdx.z;
  f32x4 acc[4][4];
  gemm_mainloop((const char*)Xb + (size_t)mb * 1024,
                (const char*)(Wts + (size_t)mode * 262144) + (size_t)nb * 1024,
                smem, smem + 16384, acc);
  const int wr = ((tid >> 7) & 1) * 64, wc = ((tid >> 6) & 1) * 64;
  const float qs = 0.18033688011112042f;  // DH^-0.5 * log2(e)
#pragma unroll
  for (int mt = 0; mt < 4; mt++)
#pragma unroll
    for (int nt = 0; nt < 4; nt++)
#pragma unroll
      for (int r = 0; r < 4; r++) {
        int m = mb + wr + mt * 16 + g * 4 + r;       // global row (b*4096+n)
        int cc = nb + wc + nt * 16 + lr;             // col (h*64+d)
        float v = acc[mt][nt][r];
        int b = m >> 12, ns = m & 4095, h = cc >> 6, d = cc & 63;
        if (mode == 0)
          Qo[((size_t)(b * 8 + h) * 4096 + ns) * 64 + d] = (bf16)(v * qs);
        else if (mode == 1)
          Ko[((size_t)(b * 8 + h) * 4096 + ns) * 64 + d] = (bf16)v;
        else
          Vto[((size_t)(b * 8 + h) * 64 + d) * 4096 + ns] = (bf16)v;
      }
}

__global__ __launch_bounds__(256) void k_gemm_out(const bf16* __restrict__ Ob,
                                                  const bf16* __restrict__ WtO,
                                                  const float* __restrict__ bo,
                                                  float* __restrict__ out) {
  __shared__ __align__(16) char smem[32768];
  const int tid = threadIdx.x;
  const int g = (tid >> 4) & 3, lr = tid & 15;
  const int mb = blockIdx.x * 128, nb = blockIdx.y * 128;
  f32x4 acc[4][4];
  gemm_mainloop((const char*)Ob + (size_t)mb * 1024,
                (const char*)WtO + (size_t)nb * 1024, smem, smem + 16384, acc);
  const int wr = ((tid >> 7) & 1) * 64, wc = ((tid >> 6) & 1) * 64;
#pragma unroll
  for (int mt = 0; mt < 4; mt++)
#pragma unroll
    for (int nt = 0; nt < 4; nt++)
#pragma unroll
      for (int r = 0; r < 4; r++) {
        int m = mb + wr + mt * 16 + g * 4 + r;
        int cc = nb + wc + nt * 16 + lr;
        out[(size_t)m * 512 + cc] = acc[mt][nt][r] + bo[cc];
      }
}

// ---------------------------------------------------------------------------
// Flash attention. Block = 64 q-rows (4 waves x 16), loop over kv tiles of 64.
// Swapped QK^T: mfma(K,Q) -> lane holds P for q = lane&15 (row-local softmax).
// P goes through a wave-private swizzled LDS tile to re-layout C->A fragment.
__global__ __launch_bounds__(256) void k_attn(const bf16* __restrict__ Q,
                                              const bf16* __restrict__ K,
                                              const bf16* __restrict__ Vt,
                                              bf16* __restrict__ O) {
  __shared__ __align__(16) char smem[24576];  // K 8K | Vt 8K | P 4x2K
  const int tid = threadIdx.x;
  const int l = tid & 63, w = tid >> 6, g = l >> 4, lr = l & 15;
  char* sK = smem;
  char* sV = smem + 8192;
  char* sP = smem + 16384 + w * 2048;
  const int bh = blockIdx.y;                 // b*8+h
  const int q0 = blockIdx.x * 64 + w * 16;   // wave's q strip
  // Q B-fragments (reused across whole KV loop); Q already scaled
  const char* Qb = (const char*)Q + ((size_t)bh * 4096 + q0 + lr) * 128;
  bf16x8 qf0 = *(const bf16x8*)(Qb + g * 16);
  bf16x8 qf1 = *(const bf16x8*)(Qb + 64 + g * 16);
  const char* Kb = (const char*)K + (size_t)bh * 4096 * 128;
  const char* Vb = (const char*)Vt + (size_t)bh * 64 * 8192;
  f32x4 zero = {0.f, 0.f, 0.f, 0.f};
  f32x4 ao[4];
#pragma unroll
  for (int dt = 0; dt < 4; dt++) ao[dt] = zero;
  float mrun = -3.0e38f, lrun = 0.f;

  for (int t = 0; t < 64; t++) {
    const int kv0 = t * 64;
#pragma unroll
    for (int i = 0; i < 2; i++) {  // stage K (64x64) and Vt (64dx64kv), 8KB each
      int c = i * 256 + tid;
      int row = c >> 3, cl = (c & 7) ^ (row & 7);
      gload16(Kb + (size_t)(kv0 + row) * 128 + cl * 16, sK + (c & ~63) * 16);
      gload16(Vb + (size_t)row * 8192 + kv0 * 2 + cl * 16, sV + (c & ~63) * 16);
    }
    __syncthreads();
    // QK^T (swapped): simT[kv][q], lane: q=lr, kv = kt*16 + g*4 + r
    f32x4 s[4];
#pragma unroll
    for (int kt = 0; kt < 4; kt++) {
      const int row = kt * 16 + lr;
      bf16x8 kf0 = *(const bf16x8*)(sK + swz(row * 128 + g * 16));
      bf16x8 kf1 = *(const bf16x8*)(sK + swz(row * 128 + 64 + g * 16));
      f32x4 z = zero;
      z = MFMA16(kf0, qf0, z, 0, 0, 0);
      z = MFMA16(kf1, qf1, z, 0, 0, 0);
      s[kt] = z;
    }
    // online softmax (base-2; scale*log2e folded into Q)
    float mt_ = -3.0e38f;
#pragma unroll
    for (int kt = 0; kt < 4; kt++)
#pragma unroll
      for (int r = 0; r < 4; r++) mt_ = fmaxf(mt_, s[kt][r]);
    mt_ = fmaxf(mt_, __shfl_xor(mt_, 16, 64));
    mt_ = fmaxf(mt_, __shfl_xor(mt_, 32, 64));
    const float mnew = fmaxf(mrun, mt_);
    const float alpha = exp2f(mrun - mnew);
    float rsum = 0.f;
#pragma unroll
    for (int kt = 0; kt < 4; kt++) {
      float p0 = exp2f(s[kt][0] - mnew);
      float p1 = exp2f(s[kt][1] - mnew);
      float p2 = exp2f(s[kt][2] - mnew);
      float p3 = exp2f(s[kt][3] - mnew);
      rsum += (p0 + p1) + (p2 + p3);
      bf16x2 w0 = {(bf16)p0, (bf16)p1};
      bf16x2 w1 = {(bf16)p2, (bf16)p3};
      // P[q=lr][kv = kt*16 + g*4 + {0..3}] into wave-private tile
      *(bf16x2*)(sP + swz(lr * 128 + kt * 32 + g * 8)) = w0;
      *(bf16x2*)(sP + swz(lr * 128 + kt * 32 + g * 8 + 4)) = w1;
    }
    rsum += __shfl_xor(rsum, 16, 64);
    rsum += __shfl_xor(rsum, 32, 64);
    lrun = lrun * alpha + rsum;
    mrun = mnew;
    // rescale O accumulators: row of ao is q = g*4+r -> fetch alpha from lane q
    float afr[4];
#pragma unroll
    for (int r = 0; r < 4; r++) afr[r] = __shfl(alpha, g * 4 + r, 64);
#pragma unroll
    for (int dt = 0; dt < 4; dt++)
#pragma unroll
      for (int r = 0; r < 4; r++) ao[dt][r] *= afr[r];
    // PV: A = P (rows q), B = V via Vt rows d
#pragma unroll
    for (int c = 0; c < 2; c++) {
      bf16x8 pa = *(const bf16x8*)(sP + swz(lr * 128 + c * 64 + g * 16));
#pragma unroll
      for (int dt = 0; dt < 4; dt++) {
        bf16x8 vf = *(const bf16x8*)(sV + swz((dt * 16 + lr) * 128 + c * 64 + g * 16));
        ao[dt] = MFMA16(pa, vf, ao[dt], 0, 0, 0);
      }
    }
    __syncthreads();
  }
  // finalize: divide by row sum, write O (B, N, H*64) bf16
  float li[4];
#pragma unroll
  for (int r = 0; r < 4; r++) li[r] = 1.0f / __shfl(lrun, g * 4 + r, 64);
  const int b = bh >> 3, h = bh & 7;
#pragma unroll
  for (int dt = 0; dt < 4; dt++)
#pragma unroll
    for (int r = 0; r < 4; r++) {
      size_t idx = ((size_t)b * 4096 + q0 + g * 4 + r) * 512 + h * 64 + dt * 16 + lr;
      O[idx] = (bf16)(ao[dt][r] * li[r]);
    }
}

// ---------------------------------------------------------------------------
extern "C" void kernel_launch(void* const* d_in, const int* in_sizes, int n_in,
                              void* d_out, int out_size, void* d_ws, size_t ws_size,
                              hipStream_t stream) {
  (void)in_sizes; (void)n_in; (void)out_size; (void)ws_size;
  const float* x  = (const float*)d_in[0];
  const float* Wq = (const float*)d_in[1];
  const float* Wk = (const float*)d_in[2];
  const float* Wv = (const float*)d_in[3];
  const float* Wo = (const float*)d_in[4];
  const float* bo = (const float*)d_in[5];
  float* out = (float*)d_out;
  char* ws = (char*)d_ws;
  bf16* Xb  = (bf16*)(ws);
  bf16* Wts = (bf16*)(ws + 8388608);
  bf16* Qb  = (bf16*)(ws + 10485760);
  bf16* Kb  = (bf16*)(ws + 18874368);
  bf16* Vtb = (bf16*)(ws + 27262976);
  bf16* Ob  = (bf16*)(ws + 35651584);

  hipLaunchKernelGGL(k_cvt_x, dim3(4096), dim3(256), 0, stream, x, Xb);
  hipLaunchKernelGGL(k_cvt_w, dim3(4096), dim3(256), 0, stream, Wq, Wk, Wv, Wo, Wts);
  hipLaunchKernelGGL(k_gemm_qkv, dim3(64, 4, 3), dim3(256), 0, stream,
                     Xb, Wts, Qb, Kb, Vtb);
  hipLaunchKernelGGL(k_attn, dim3(64, 16), dim3(256), 0, stream, Qb, Kb, Vtb, Ob);
  hipLaunchKernelGGL(k_gemm_out, dim3(64, 4), dim3(256), 0, stream,
                     Ob, Wts + 3 * 262144, bo, out);
}

// Round 2
// 174.765 us; speedup vs baseline: 1.2752x; 1.2752x over previous
//
#include <hip/hip_runtime.h>

// ---------------------------------------------------------------------------
// CrossAttention (self-attn): B=2 N=4096 D=512 H=8 DH=64
// Pipeline: cvt(x,W) -> GEMM qkv (bf16 mfma, V stored transposed) ->
//           flash attention (mfma 32x32x16, in-register P, online softmax) ->
//           GEMM out + bias
// Workspace layout (bytes):
//   Xb   @ 0         : 8192x512 bf16   (8,388,608)
//   WtQ/K/V/O @ 8388608 : 4 x 512x512 bf16 (N-major)  (2,097,152)
//   Q    @ 10485760  : (B,H,N,DH) bf16, pre-scaled by SCALE*log2(e)
//   K    @ 18874368  : (B,H,N,DH) bf16
//   Vt   @ 27262976  : (B,H,DH,N) bf16  (transposed for PV B-fragments)
//   O    @ 35651584  : (B,N,H*DH) bf16
// ---------------------------------------------------------------------------

typedef __bf16 bf16;
typedef __bf16 bf16x2 __attribute__((ext_vector_type(2)));
typedef __bf16 bf16x4 __attribute__((ext_vector_type(4)));
typedef __bf16 bf16x8 __attribute__((ext_vector_type(8)));
typedef float  f32x4  __attribute__((ext_vector_type(4)));
typedef float  f32x16 __attribute__((ext_vector_type(16)));

#define MFMA16 __builtin_amdgcn_mfma_f32_16x16x32_bf16
#define MFMA32 __builtin_amdgcn_mfma_f32_32x32x16_bf16

// XOR swizzle for 128B-row LDS tiles: byte ^= ((row&7)<<4)
__device__ __forceinline__ int swz(int b) { return b ^ ((b >> 3) & 0x70); }

__device__ __forceinline__ void gload16(const void* g, void* l) {
  __builtin_amdgcn_global_load_lds(
      (const __attribute__((address_space(1))) unsigned int*)g,
      (__attribute__((address_space(3))) unsigned int*)l, 16, 0, 0);
}

__device__ __forceinline__ unsigned pk2(float a, float b) {
  union { bf16x2 h; unsigned u; } x;
  x.h[0] = (bf16)a; x.h[1] = (bf16)b;
  return x.u;
}

// ---------------------------------------------------------------------------
__global__ __launch_bounds__(256) void k_cvt_x(const float* __restrict__ x,
                                               bf16* __restrict__ xb) {
  int i = (blockIdx.x * 256 + threadIdx.x) * 4;
  f32x4 v = *(const f32x4*)(x + i);
  bf16x4 o;
  o[0] = (bf16)v[0]; o[1] = (bf16)v[1]; o[2] = (bf16)v[2]; o[3] = (bf16)v[3];
  *(bf16x4*)(xb + i) = o;
}

__global__ __launch_bounds__(256) void k_cvt_w(const float* __restrict__ Wq,
                                               const float* __restrict__ Wk,
                                               const float* __restrict__ Wv,
                                               const float* __restrict__ Wo,
                                               bf16* __restrict__ Wts) {
  int t = blockIdx.x * 256 + threadIdx.x;       // 0 .. 4*512*512-1
  int w = t >> 18, idx = t & 262143;
  int k = idx >> 9, n = idx & 511;
  const float* W = (w == 0) ? Wq : (w == 1) ? Wk : (w == 2) ? Wv : Wo;
  Wts[(size_t)w * 262144 + n * 512 + k] = (bf16)W[k * 512 + n];
}

// ---------------------------------------------------------------------------
// 128x128 tile GEMM mainloop, K=512, BK=64, 4 waves (2x2 of 64x64)
__device__ __forceinline__ void gemm_mainloop(const char* Ag, const char* Bg,
                                              char* sA, char* sB, f32x4 acc[4][4]) {
  const int tid = threadIdx.x;
  const int g = (tid >> 4) & 3, lr = tid & 15;
  const int wr = ((tid >> 7) & 1) * 64, wc = ((tid >> 6) & 1) * 64;
  f32x4 zero = {0.f, 0.f, 0.f, 0.f};
#pragma unroll
  for (int mt = 0; mt < 4; mt++)
#pragma unroll
    for (int nt = 0; nt < 4; nt++) acc[mt][nt] = zero;

  for (int k0 = 0; k0 < 512; k0 += 64) {
#pragma unroll
    for (int i = 0; i < 4; i++) {  // A tile: 128 rows x 64 k (16KB)
      int c = i * 256 + tid;
      int row = c >> 3, cl = (c & 7) ^ (row & 7);   // pre-swizzled source chunk
      gload16(Ag + row * 1024 + k0 * 2 + cl * 16, sA + (c & ~63) * 16);
    }
#pragma unroll
    for (int i = 0; i < 4; i++) {  // B tile (N-major weights): 128 rows x 64 k
      int c = i * 256 + tid;
      int row = c >> 3, cl = (c & 7) ^ (row & 7);
      gload16(Bg + row * 1024 + k0 * 2 + cl * 16, sB + (c & ~63) * 16);
    }
    __syncthreads();
#pragma unroll
    for (int kk = 0; kk < 2; kk++) {
      bf16x8 af[4], bfr[4];
#pragma unroll
      for (int mt = 0; mt < 4; mt++)
        af[mt] = *(const bf16x8*)(sA + swz((wr + mt * 16 + lr) * 128 + kk * 64 + g * 16));
#pragma unroll
      for (int nt = 0; nt < 4; nt++)
        bfr[nt] = *(const bf16x8*)(sB + swz((wc + nt * 16 + lr) * 128 + kk * 64 + g * 16));
#pragma unroll
      for (int mt = 0; mt < 4; mt++)
#pragma unroll
        for (int nt = 0; nt < 4; nt++)
          acc[mt][nt] = MFMA16(af[mt], bfr[nt], acc[mt][nt], 0, 0, 0);
    }
    __syncthreads();
  }
}

// z = 0:Q (scaled), 1:K, 2:V (transposed store)
__global__ __launch_bounds__(256) void k_gemm_qkv(const bf16* __restrict__ Xb,
                                                  const bf16* __restrict__ Wts,
                                                  bf16* __restrict__ Qo,
                                                  bf16* __restrict__ Ko,
                                                  bf16* __restrict__ Vto) {
  __shared__ __align__(16) char smem[32768];
  const int tid = threadIdx.x;
  const int g = (tid >> 4) & 3, lr = tid & 15;
  const int mb = blockIdx.x * 128, nb = blockIdx.y * 128;
  const int mode = blockIdx.z;
  f32x4 acc[4][4];
  gemm_mainloop((const char*)Xb + (size_t)mb * 1024,
                (const char*)(Wts + (size_t)mode * 262144) + (size_t)nb * 1024,
                smem, smem + 16384, acc);
  const int wr = ((tid >> 7) & 1) * 64, wc = ((tid >> 6) & 1) * 64;
  const float qs = 0.18033688011112042f;  // DH^-0.5 * log2(e)
#pragma unroll
  for (int mt = 0; mt < 4; mt++)
#pragma unroll
    for (int nt = 0; nt < 4; nt++)
#pragma unroll
      for (int r = 0; r < 4; r++) {
        int m = mb + wr + mt * 16 + g * 4 + r;       // global row (b*4096+n)
        int cc = nb + wc + nt * 16 + lr;             // col (h*64+d)
        float v = acc[mt][nt][r];
        int b = m >> 12, ns = m & 4095, h = cc >> 6, d = cc & 63;
        if (mode == 0)
          Qo[((size_t)(b * 8 + h) * 4096 + ns) * 64 + d] = (bf16)(v * qs);
        else if (mode == 1)
          Ko[((size_t)(b * 8 + h) * 4096 + ns) * 64 + d] = (bf16)v;
        else
          Vto[((size_t)(b * 8 + h) * 64 + d) * 4096 + ns] = (bf16)v;
      }
}

__global__ __launch_bounds__(256) void k_gemm_out(const bf16* __restrict__ Ob,
                                                  const bf16* __restrict__ WtO,
                                                  const float* __restrict__ bo,
                                                  float* __restrict__ out) {
  __shared__ __align__(16) char smem[32768];
  const int tid = threadIdx.x;
  const int g = (tid >> 4) & 3, lr = tid & 15;
  const int mb = blockIdx.x * 128, nb = blockIdx.y * 128;
  f32x4 acc[4][4];
  gemm_mainloop((const char*)Ob + (size_t)mb * 1024,
                (const char*)WtO + (size_t)nb * 1024, smem, smem + 16384, acc);
  const int wr = ((tid >> 7) & 1) * 64, wc = ((tid >> 6) & 1) * 64;
#pragma unroll
  for (int mt = 0; mt < 4; mt++)
#pragma unroll
    for (int nt = 0; nt < 4; nt++)
#pragma unroll
      for (int r = 0; r < 4; r++) {
        int m = mb + wr + mt * 16 + g * 4 + r;
        int cc = nb + wc + nt * 16 + lr;
        out[(size_t)m * 512 + cc] = acc[mt][nt][r] + bo[cc];
      }
}

// ---------------------------------------------------------------------------
// Flash attention, 32x32x16 MFMA, 4 warps x 32 q-rows, KVBLK=64, dbuf LDS.
// Swapped QK^T: S^T[kv][q], q = lane&31, kv = (r&3)+8*(r>>2)+4*(lane>>5) per
// 32-chunk. Softmax per-lane (row = own q) + one shfl_xor(32). P -> A-frag
// in-register via bf16 pack + half-wave exchange. PV B-frag from Vt rows.
__device__ __forceinline__ void stage_kv(const char* Kb, const char* Vb,
                                         char* smem, int t, int tid) {
  char* bK = smem + (t & 1) * 16384;
  char* bV = bK + 8192;
  const size_t kv0 = (size_t)t * 64;
#pragma unroll
  for (int i = 0; i < 2; i++) {
    int c = i * 256 + tid;
    int row = c >> 3, cl = (c & 7) ^ (row & 7);
    gload16(Kb + (kv0 + row) * 128 + cl * 16, bK + (c & ~63) * 16);
    gload16(Vb + (size_t)row * 8192 + kv0 * 2 + cl * 16, bV + (c & ~63) * 16);
  }
}

__global__ __launch_bounds__(256) void k_attn(const bf16* __restrict__ Q,
                                              const bf16* __restrict__ K,
                                              const bf16* __restrict__ Vt,
                                              bf16* __restrict__ O) {
  __shared__ __align__(16) char smem[32768];  // 2 x (K 8K | Vt 8K)
  const int tid = threadIdx.x;
  const int l = tid & 63, w = tid >> 6, lo = l & 31, hi = l >> 5;
  const int bh = blockIdx.y;                  // b*8+h
  const int q0 = blockIdx.x * 128 + w * 32;   // warp's q strip
  // Q B-fragments: qf[ks] = Q[q0+lo][ks*16 + hi*8 .. +7] (Q pre-scaled)
  const char* Qp = (const char*)Q + ((size_t)bh * 4096 + q0 + lo) * 128;
  bf16x8 qf[4];
#pragma unroll
  for (int ks = 0; ks < 4; ks++) qf[ks] = *(const bf16x8*)(Qp + ks * 32 + hi * 16);
  const char* Kb = (const char*)K + (size_t)bh * 4096 * 128;
  const char* Vb = (const char*)Vt + (size_t)bh * 64 * 8192;

  f32x16 acc0 = {0.f}, acc1 = {0.f};
  float mrun = -3.0e38f, lsum = 0.f;

  stage_kv(Kb, Vb, smem, 0, tid);
  __syncthreads();

  for (int t = 0; t < 64; t++) {
    if (t < 63) stage_kv(Kb, Vb, smem, t + 1, tid);  // async prefetch
    char* bK = smem + (t & 1) * 16384;
    char* bV = bK + 8192;
    // ---- QK^T: S^T[kv 64][q 32], two 32-kv chunks
    f32x16 s0 = {0.f}, s1 = {0.f};
#pragma unroll
    for (int ks = 0; ks < 4; ks++) {
      bf16x8 kf0 = *(const bf16x8*)(bK + swz(lo * 128 + ks * 32 + hi * 16));
      bf16x8 kf1 = *(const bf16x8*)(bK + swz((32 + lo) * 128 + ks * 32 + hi * 16));
      s0 = MFMA32(kf0, qf[ks], s0, 0, 0, 0);
      s1 = MFMA32(kf1, qf[ks], s1, 0, 0, 0);
    }
    // ---- row max (own q = lo), tree + one cross-half exchange
    float mx[16];
#pragma unroll
    for (int r = 0; r < 16; r++) mx[r] = fmaxf(s0[r], s1[r]);
#pragma unroll
    for (int r = 0; r < 8; r++) mx[r] = fmaxf(mx[r], mx[r + 8]);
#pragma unroll
    for (int r = 0; r < 4; r++) mx[r] = fmaxf(mx[r], mx[r + 4]);
    float pmax = fmaxf(fmaxf(mx[0], mx[1]), fmaxf(mx[2], mx[3]));
    pmax = fmaxf(pmax, __shfl_xor(pmax, 32, 64));
    // ---- defer-max (THR=8 in log2 domain)
    if (t == 0) {
      mrun = pmax;
    } else if (!__all(pmax - mrun <= 8.0f)) {
      float mnew = fmaxf(mrun, pmax);
      float alpha = exp2f(mrun - mnew);
      lsum *= alpha;
#pragma unroll
      for (int r = 0; r < 16; r++) {
        float af = __shfl(alpha, (r & 3) + 8 * (r >> 2) + 4 * hi, 64);
        acc0[r] *= af; acc1[r] *= af;
      }
      mrun = mnew;
    }
    // ---- p = exp2(s - m), row sum
#pragma unroll
    for (int r = 0; r < 16; r++) {
      s0[r] = __builtin_amdgcn_exp2f(s0[r] - mrun);
      s1[r] = __builtin_amdgcn_exp2f(s1[r] - mrun);
    }
    float sm[16];
#pragma unroll
    for (int r = 0; r < 16; r++) sm[r] = s0[r] + s1[r];
#pragma unroll
    for (int r = 0; r < 8; r++) sm[r] += sm[r + 8];
#pragma unroll
    for (int r = 0; r < 4; r++) sm[r] += sm[r + 4];
    float rs = (sm[0] + sm[1]) + (sm[2] + sm[3]);
    rs += __shfl_xor(rs, 32, 64);
    lsum += rs;
    // ---- pack P into A-fragments (in-register, half-wave exchange)
    // chunk c, block tb: words from regs base tb*8:
    //   A0=pk(p0,p1) A1=pk(p2,p3) B0=pk(p4,p5) B1=pk(p6,p7)
    //   w0 = hi? xB0 : A0 ; w1 = hi? xB1 : A1 ; w2 = hi? B0 : xA0 ; w3 = hi? B1 : xA1
    union U8 { unsigned u[4]; bf16x8 v; };
    bf16x8 pa[4];
#pragma unroll
    for (int c = 0; c < 2; c++) {
#pragma unroll
      for (int tb = 0; tb < 2; tb++) {
        int b = tb * 8;
        float p0, p1, p2, p3, p4, p5, p6, p7;
        if (c == 0) {
          p0 = s0[b + 0]; p1 = s0[b + 1]; p2 = s0[b + 2]; p3 = s0[b + 3];
          p4 = s0[b + 4]; p5 = s0[b + 5]; p6 = s0[b + 6]; p7 = s0[b + 7];
        } else {
          p0 = s1[b + 0]; p1 = s1[b + 1]; p2 = s1[b + 2]; p3 = s1[b + 3];
          p4 = s1[b + 4]; p5 = s1[b + 5]; p6 = s1[b + 6]; p7 = s1[b + 7];
        }
        unsigned A0 = pk2(p0, p1), A1 = pk2(p2, p3);
        unsigned B0 = pk2(p4, p5), B1 = pk2(p6, p7);
        unsigned xA0 = __shfl_xor(A0, 32, 64), xA1 = __shfl_xor(A1, 32, 64);
        unsigned xB0 = __shfl_xor(B0, 32, 64), xB1 = __shfl_xor(B1, 32, 64);
        U8 pu;
        pu.u[0] = hi ? xB0 : A0;
        pu.u[1] = hi ? xB1 : A1;
        pu.u[2] = hi ? B0 : xA0;
        pu.u[3] = hi ? B1 : xA1;
        pa[c * 2 + tb] = pu.v;
      }
    }
    // ---- PV: O[32q][64d] += P[32q][64kv] V[64kv][64d]
#pragma unroll
    for (int ks = 0; ks < 4; ks++) {
      bf16x8 vf0 = *(const bf16x8*)(bV + swz(lo * 128 + ks * 32 + hi * 16));
      bf16x8 vf1 = *(const bf16x8*)(bV + swz((32 + lo) * 128 + ks * 32 + hi * 16));
      acc0 = MFMA32(pa[ks], vf0, acc0, 0, 0, 0);
      acc1 = MFMA32(pa[ks], vf1, acc1, 0, 0, 0);
    }
    __syncthreads();
  }
  // ---- epilogue: divide by row sum, write O (B, N, H*64) bf16
  const int b = bh >> 3, h = bh & 7;
#pragma unroll
  for (int r = 0; r < 16; r++) {
    int qrow = (r & 3) + 8 * (r >> 2) + 4 * hi;
    float inv = 1.0f / __shfl(lsum, qrow, 64);
    size_t base = ((size_t)b * 4096 + q0 + qrow) * 512 + h * 64 + lo;
    O[base] = (bf16)(acc0[r] * inv);
    O[base + 32] = (bf16)(acc1[r] * inv);
  }
}

// ---------------------------------------------------------------------------
extern "C" void kernel_launch(void* const* d_in, const int* in_sizes, int n_in,
                              void* d_out, int out_size, void* d_ws, size_t ws_size,
                              hipStream_t stream) {
  (void)in_sizes; (void)n_in; (void)out_size; (void)ws_size;
  const float* x  = (const float*)d_in[0];
  const float* Wq = (const float*)d_in[1];
  const float* Wk = (const float*)d_in[2];
  const float* Wv = (const float*)d_in[3];
  const float* Wo = (const float*)d_in[4];
  const float* bo = (const float*)d_in[5];
  float* out = (float*)d_out;
  char* ws = (char*)d_ws;
  bf16* Xb  = (bf16*)(ws);
  bf16* Wts = (bf16*)(ws + 8388608);
  bf16* Qb  = (bf16*)(ws + 10485760);
  bf16* Kb  = (bf16*)(ws + 18874368);
  bf16* Vtb = (bf16*)(ws + 27262976);
  bf16* Ob  = (bf16*)(ws + 35651584);

  hipLaunchKernelGGL(k_cvt_x, dim3(4096), dim3(256), 0, stream, x, Xb);
  hipLaunchKernelGGL(k_cvt_w, dim3(4096), dim3(256), 0, stream, Wq, Wk, Wv, Wo, Wts);
  hipLaunchKernelGGL(k_gemm_qkv, dim3(64, 4, 3), dim3(256), 0, stream,
                     Xb, Wts, Qb, Kb, Vtb);
  hipLaunchKernelGGL(k_attn, dim3(32, 16), dim3(256), 0, stream, Qb, Kb, Vtb, Ob);
  hipLaunchKernelGGL(k_gemm_out, dim3(64, 4), dim3(256), 0, stream,
                     Ob, Wts + 3 * 262144, bo, out);
}

// Round 3
// 156.017 us; speedup vs baseline: 1.4284x; 1.1202x over previous
//
#include <hip/hip_runtime.h>

// ---------------------------------------------------------------------------
// CrossAttention (self-attn): B=2 N=4096 D=512 H=8 DH=64
// Pipeline: cvt(x,W) -> GEMM qkv (bf16 mfma, V stored transposed) ->
//           flash attention (mfma 32x32x16, KV-split x2 per block, in-register
//           P, online softmax, LDS combine) -> GEMM out + bias
// Workspace layout (bytes):
//   Xb   @ 0         : 8192x512 bf16   (8,388,608)
//   WtQ/K/V/O @ 8388608 : 4 x 512x512 bf16 (N-major)  (2,097,152)
//   Q    @ 10485760  : (B,H,N,DH) bf16, pre-scaled by SCALE*log2(e)
//   K    @ 18874368  : (B,H,N,DH) bf16
//   Vt   @ 27262976  : (B,H,DH,N) bf16  (transposed for PV B-fragments)
//   O    @ 35651584  : (B,N,H*DH) bf16
// ---------------------------------------------------------------------------

typedef __bf16 bf16;
typedef __bf16 bf16x2 __attribute__((ext_vector_type(2)));
typedef __bf16 bf16x4 __attribute__((ext_vector_type(4)));
typedef __bf16 bf16x8 __attribute__((ext_vector_type(8)));
typedef float  f32x4  __attribute__((ext_vector_type(4)));
typedef float  f32x16 __attribute__((ext_vector_type(16)));

#define MFMA16 __builtin_amdgcn_mfma_f32_16x16x32_bf16
#define MFMA32 __builtin_amdgcn_mfma_f32_32x32x16_bf16

// XOR swizzle for 128B-row LDS tiles: byte ^= ((row&7)<<4)
__device__ __forceinline__ int swz(int b) { return b ^ ((b >> 3) & 0x70); }

__device__ __forceinline__ void gload16(const void* g, void* l) {
  __builtin_amdgcn_global_load_lds(
      (const __attribute__((address_space(1))) unsigned int*)g,
      (__attribute__((address_space(3))) unsigned int*)l, 16, 0, 0);
}

__device__ __forceinline__ unsigned pk2(float a, float b) {
  union { bf16x2 h; unsigned u; } x;
  x.h[0] = (bf16)a; x.h[1] = (bf16)b;
  return x.u;
}

// ---------------------------------------------------------------------------
__global__ __launch_bounds__(256) void k_cvt_x(const float* __restrict__ x,
                                               bf16* __restrict__ xb) {
  int i = (blockIdx.x * 256 + threadIdx.x) * 4;
  f32x4 v = *(const f32x4*)(x + i);
  bf16x4 o;
  o[0] = (bf16)v[0]; o[1] = (bf16)v[1]; o[2] = (bf16)v[2]; o[3] = (bf16)v[3];
  *(bf16x4*)(xb + i) = o;
}

__global__ __launch_bounds__(256) void k_cvt_w(const float* __restrict__ Wq,
                                               const float* __restrict__ Wk,
                                               const float* __restrict__ Wv,
                                               const float* __restrict__ Wo,
                                               bf16* __restrict__ Wts) {
  int t = blockIdx.x * 256 + threadIdx.x;       // 0 .. 4*512*512-1
  int w = t >> 18, idx = t & 262143;
  int k = idx >> 9, n = idx & 511;
  const float* W = (w == 0) ? Wq : (w == 1) ? Wk : (w == 2) ? Wv : Wo;
  Wts[(size_t)w * 262144 + n * 512 + k] = (bf16)W[k * 512 + n];
}

// ---------------------------------------------------------------------------
// 128x128 tile GEMM mainloop, K=512, BK=64, 4 waves (2x2 of 64x64)
__device__ __forceinline__ void gemm_mainloop(const char* Ag, const char* Bg,
                                              char* sA, char* sB, f32x4 acc[4][4]) {
  const int tid = threadIdx.x;
  const int g = (tid >> 4) & 3, lr = tid & 15;
  const int wr = ((tid >> 7) & 1) * 64, wc = ((tid >> 6) & 1) * 64;
  f32x4 zero = {0.f, 0.f, 0.f, 0.f};
#pragma unroll
  for (int mt = 0; mt < 4; mt++)
#pragma unroll
    for (int nt = 0; nt < 4; nt++) acc[mt][nt] = zero;

  for (int k0 = 0; k0 < 512; k0 += 64) {
#pragma unroll
    for (int i = 0; i < 4; i++) {  // A tile: 128 rows x 64 k (16KB)
      int c = i * 256 + tid;
      int row = c >> 3, cl = (c & 7) ^ (row & 7);   // pre-swizzled source chunk
      gload16(Ag + row * 1024 + k0 * 2 + cl * 16, sA + (c & ~63) * 16);
    }
#pragma unroll
    for (int i = 0; i < 4; i++) {  // B tile (N-major weights): 128 rows x 64 k
      int c = i * 256 + tid;
      int row = c >> 3, cl = (c & 7) ^ (row & 7);
      gload16(Bg + row * 1024 + k0 * 2 + cl * 16, sB + (c & ~63) * 16);
    }
    __syncthreads();
#pragma unroll
    for (int kk = 0; kk < 2; kk++) {
      bf16x8 af[4], bfr[4];
#pragma unroll
      for (int mt = 0; mt < 4; mt++)
        af[mt] = *(const bf16x8*)(sA + swz((wr + mt * 16 + lr) * 128 + kk * 64 + g * 16));
#pragma unroll
      for (int nt = 0; nt < 4; nt++)
        bfr[nt] = *(const bf16x8*)(sB + swz((wc + nt * 16 + lr) * 128 + kk * 64 + g * 16));
#pragma unroll
      for (int mt = 0; mt < 4; mt++)
#pragma unroll
        for (int nt = 0; nt < 4; nt++)
          acc[mt][nt] = MFMA16(af[mt], bfr[nt], acc[mt][nt], 0, 0, 0);
    }
    __syncthreads();
  }
}

// z = 0:Q (scaled), 1:K, 2:V (transposed store)
__global__ __launch_bounds__(256) void k_gemm_qkv(const bf16* __restrict__ Xb,
                                                  const bf16* __restrict__ Wts,
                                                  bf16* __restrict__ Qo,
                                                  bf16* __restrict__ Ko,
                                                  bf16* __restrict__ Vto) {
  __shared__ __align__(16) char smem[32768];
  const int tid = threadIdx.x;
  const int g = (tid >> 4) & 3, lr = tid & 15;
  const int mb = blockIdx.x * 128, nb = blockIdx.y * 128;
  const int mode = blockIdx.z;
  f32x4 acc[4][4];
  gemm_mainloop((const char*)Xb + (size_t)mb * 1024,
                (const char*)(Wts + (size_t)mode * 262144) + (size_t)nb * 1024,
                smem, smem + 16384, acc);
  const int wr = ((tid >> 7) & 1) * 64, wc = ((tid >> 6) & 1) * 64;
  const float qs = 0.18033688011112042f;  // DH^-0.5 * log2(e)
#pragma unroll
  for (int mt = 0; mt < 4; mt++)
#pragma unroll
    for (int nt = 0; nt < 4; nt++)
#pragma unroll
      for (int r = 0; r < 4; r++) {
        int m = mb + wr + mt * 16 + g * 4 + r;       // global row (b*4096+n)
        int cc = nb + wc + nt * 16 + lr;             // col (h*64+d)
        float v = acc[mt][nt][r];
        int b = m >> 12, ns = m & 4095, h = cc >> 6, d = cc & 63;
        if (mode == 0)
          Qo[((size_t)(b * 8 + h) * 4096 + ns) * 64 + d] = (bf16)(v * qs);
        else if (mode == 1)
          Ko[((size_t)(b * 8 + h) * 4096 + ns) * 64 + d] = (bf16)v;
        else
          Vto[((size_t)(b * 8 + h) * 64 + d) * 4096 + ns] = (bf16)v;
      }
}

__global__ __launch_bounds__(256) void k_gemm_out(const bf16* __restrict__ Ob,
                                                  const bf16* __restrict__ WtO,
                                                  const float* __restrict__ bo,
                                                  float* __restrict__ out) {
  __shared__ __align__(16) char smem[32768];
  const int tid = threadIdx.x;
  const int g = (tid >> 4) & 3, lr = tid & 15;
  const int mb = blockIdx.x * 128, nb = blockIdx.y * 128;
  f32x4 acc[4][4];
  gemm_mainloop((const char*)Ob + (size_t)mb * 1024,
                (const char*)WtO + (size_t)nb * 1024, smem, smem + 16384, acc);
  const int wr = ((tid >> 7) & 1) * 64, wc = ((tid >> 6) & 1) * 64;
#pragma unroll
  for (int mt = 0; mt < 4; mt++)
#pragma unroll
    for (int nt = 0; nt < 4; nt++)
#pragma unroll
      for (int r = 0; r < 4; r++) {
        int m = mb + wr + mt * 16 + g * 4 + r;
        int cc = nb + wc + nt * 16 + lr;
        out[(size_t)m * 512 + cc] = acc[mt][nt][r] + bo[cc];
      }
}

// ---------------------------------------------------------------------------
// Flash attention, 32x32x16 MFMA. Block = 512 threads = 8 warps:
//   warp w: q-strip (w&3)*32, KV-half (w>>2). Each half loops 32 tiles of 64.
//   Warp pairs (w, w^4) combine partial (m, l, acc) through LDS at the end.
__device__ __forceinline__ void stage_kv(const char* Kh, const char* Vh,
                                         char* lbase, int t, int tid2) {
  char* bK = lbase + (t & 1) * 16384;
  char* bV = bK + 8192;
  const size_t kv0 = (size_t)t * 64;
#pragma unroll
  for (int i = 0; i < 2; i++) {
    int c = i * 256 + tid2;
    int row = c >> 3, cl = (c & 7) ^ (row & 7);
    gload16(Kh + (kv0 + row) * 128 + cl * 16, bK + (c & ~63) * 16);
    gload16(Vh + (size_t)row * 8192 + kv0 * 2 + cl * 16, bV + (c & ~63) * 16);
  }
}

__global__ __launch_bounds__(512, 4) void k_attn(const bf16* __restrict__ Q,
                                                 const bf16* __restrict__ K,
                                                 const bf16* __restrict__ Vt,
                                                 bf16* __restrict__ O) {
  __shared__ __align__(16) char smem[65536];  // 2 halves x dbuf x (K 8K | V 8K)
  const int tid = threadIdx.x;
  const int l = tid & 63, w = tid >> 6, lo = l & 31, hi = l >> 5;
  const int strip = w & 3, half = w >> 2;
  const int tid2 = tid & 255;
  const int bh = blockIdx.y;                       // b*8+h
  const int q0 = blockIdx.x * 128 + strip * 32;    // warp's q strip
  // Q B-fragments: qf[ks] = Q[q0+lo][ks*16 + hi*8 .. +7] (Q pre-scaled)
  const char* Qp = (const char*)Q + ((size_t)bh * 4096 + q0 + lo) * 128;
  bf16x8 qf[4];
#pragma unroll
  for (int ks = 0; ks < 4; ks++) qf[ks] = *(const bf16x8*)(Qp + ks * 32 + hi * 16);
  const char* Kh = (const char*)K + (size_t)bh * 4096 * 128 + (size_t)half * 2048 * 128;
  const char* Vh = (const char*)Vt + (size_t)bh * 64 * 8192 + (size_t)half * 4096;
  char* lbase = smem + half * 32768;

  f32x16 acc0 = {0.f}, acc1 = {0.f};
  float mrun = -3.0e38f, lsum = 0.f;

  stage_kv(Kh, Vh, lbase, 0, tid2);
  __syncthreads();

  for (int t = 0; t < 32; t++) {
    if (t < 31) stage_kv(Kh, Vh, lbase, t + 1, tid2);  // async prefetch
    char* bK = lbase + (t & 1) * 16384;
    char* bV = bK + 8192;
    // ---- QK^T: S^T[kv 64][q 32], two 32-kv chunks
    f32x16 s0 = {0.f}, s1 = {0.f};
    __builtin_amdgcn_s_setprio(1);
#pragma unroll
    for (int ks = 0; ks < 4; ks++) {
      bf16x8 kf0 = *(const bf16x8*)(bK + swz(lo * 128 + ks * 32 + hi * 16));
      bf16x8 kf1 = *(const bf16x8*)(bK + swz((32 + lo) * 128 + ks * 32 + hi * 16));
      s0 = MFMA32(kf0, qf[ks], s0, 0, 0, 0);
      s1 = MFMA32(kf1, qf[ks], s1, 0, 0, 0);
    }
    __builtin_amdgcn_s_setprio(0);
    // ---- row max (own q = lo), tree + one cross-half exchange
    float mx[16];
#pragma unroll
    for (int r = 0; r < 16; r++) mx[r] = fmaxf(s0[r], s1[r]);
#pragma unroll
    for (int r = 0; r < 8; r++) mx[r] = fmaxf(mx[r], mx[r + 8]);
#pragma unroll
    for (int r = 0; r < 4; r++) mx[r] = fmaxf(mx[r], mx[r + 4]);
    float pmax = fmaxf(fmaxf(mx[0], mx[1]), fmaxf(mx[2], mx[3]));
    pmax = fmaxf(pmax, __shfl_xor(pmax, 32, 64));
    // ---- defer-max (THR=8 in log2 domain)
    if (t == 0) {
      mrun = pmax;
    } else if (!__all(pmax - mrun <= 8.0f)) {
      float mnew = fmaxf(mrun, pmax);
      float alpha = __builtin_amdgcn_exp2f(mrun - mnew);
      lsum *= alpha;
#pragma unroll
      for (int r = 0; r < 16; r++) {
        float af = __shfl(alpha, (r & 3) + 8 * (r >> 2) + 4 * hi, 64);
        acc0[r] *= af; acc1[r] *= af;
      }
      mrun = mnew;
    }
    // ---- p = exp2(s - m), row sum
#pragma unroll
    for (int r = 0; r < 16; r++) {
      s0[r] = __builtin_amdgcn_exp2f(s0[r] - mrun);
      s1[r] = __builtin_amdgcn_exp2f(s1[r] - mrun);
    }
    float sm[16];
#pragma unroll
    for (int r = 0; r < 16; r++) sm[r] = s0[r] + s1[r];
#pragma unroll
    for (int r = 0; r < 8; r++) sm[r] += sm[r + 8];
#pragma unroll
    for (int r = 0; r < 4; r++) sm[r] += sm[r + 4];
    float rs = (sm[0] + sm[1]) + (sm[2] + sm[3]);
    rs += __shfl_xor(rs, 32, 64);
    lsum += rs;
    // ---- pack P into A-fragments: cvt_pk + permlane32_swap (T12)
    auto packhalf = [&](const f32x16& s, int base) -> bf16x8 {
      unsigned A0 = pk2(s[base + 0], s[base + 1]), A1 = pk2(s[base + 2], s[base + 3]);
      unsigned B0 = pk2(s[base + 4], s[base + 5]), B1 = pk2(s[base + 6], s[base + 7]);
      // swap A.hi-lanes <-> B.lo-lanes: A' = w(lo:own A01, hi:partner B01), B' = w(lo:partner A01, hi:own B01)
      asm("v_permlane32_swap_b32 %0, %1" : "+v"(A0), "+v"(B0));
      asm("v_permlane32_swap_b32 %0, %1" : "+v"(A1), "+v"(B1));
      union U8 { unsigned u[4]; bf16x8 v; } pu;
      pu.u[0] = A0; pu.u[1] = A1; pu.u[2] = B0; pu.u[3] = B1;
      return pu.v;
    };
    bf16x8 pa[4];
    pa[0] = packhalf(s0, 0);
    pa[1] = packhalf(s0, 8);
    pa[2] = packhalf(s1, 0);
    pa[3] = packhalf(s1, 8);
    // ---- PV: O[32q][64d] += P[32q][64kv] V[64kv][64d]
    __builtin_amdgcn_s_setprio(1);
#pragma unroll
    for (int ks = 0; ks < 4; ks++) {
      bf16x8 vf0 = *(const bf16x8*)(bV + swz(lo * 128 + ks * 32 + hi * 16));
      bf16x8 vf1 = *(const bf16x8*)(bV + swz((32 + lo) * 128 + ks * 32 + hi * 16));
      acc0 = MFMA32(pa[ks], vf0, acc0, 0, 0, 0);
      acc1 = MFMA32(pa[ks], vf1, acc1, 0, 0, 0);
    }
    __builtin_amdgcn_s_setprio(0);
    __syncthreads();
  }
  // ---- combine halves via LDS (warp pairs w <-> w^4), then write O
  float* accStash = (float*)smem;            // [4 strips][32 q][64 d] f32 = 32KB
  float* mArr = (float*)(smem + 32768);      // [8 warps][32 q]
  float* lArr = (float*)(smem + 36864);      // [8 warps][32 q]
  float* cArr = (float*)(smem + 40960);      // [8 warps][32 q]: exp2(m-mn)/ln
  if (l < 32) { mArr[w * 32 + lo] = mrun; lArr[w * 32 + lo] = lsum; }
  __syncthreads();
  if (l < 32) {
    float mP = mArr[(w ^ 4) * 32 + lo];
    float lP = lArr[(w ^ 4) * 32 + lo];
    float mn = fmaxf(mrun, mP);
    float wS = __builtin_amdgcn_exp2f(mrun - mn);
    float wP = __builtin_amdgcn_exp2f(mP - mn);
    cArr[w * 32 + lo] = wS / (lsum * wS + lP * wP);
  }
  __syncthreads();
  if (half == 1) {  // stash scaled partial
#pragma unroll
    for (int r = 0; r < 16; r++) {
      int qrow = (r & 3) + 8 * (r >> 2) + 4 * hi;
      float cf = cArr[w * 32 + qrow];
      accStash[(strip * 32 + qrow) * 64 + lo] = acc0[r] * cf;
      accStash[(strip * 32 + qrow) * 64 + lo + 32] = acc1[r] * cf;
    }
  }
  __syncthreads();
  if (half == 0) {  // merge + write O (B, N, H*64) bf16
    const int b = bh >> 3, h = bh & 7;
#pragma unroll
    for (int r = 0; r < 16; r++) {
      int qrow = (r & 3) + 8 * (r >> 2) + 4 * hi;
      float cf = cArr[w * 32 + qrow];
      float o0 = acc0[r] * cf + accStash[(strip * 32 + qrow) * 64 + lo];
      float o1 = acc1[r] * cf + accStash[(strip * 32 + qrow) * 64 + lo + 32];
      size_t base = ((size_t)b * 4096 + q0 + qrow) * 512 + h * 64 + lo;
      O[base] = (bf16)o0;
      O[base + 32] = (bf16)o1;
    }
  }
}

// ---------------------------------------------------------------------------
extern "C" void kernel_launch(void* const* d_in, const int* in_sizes, int n_in,
                              void* d_out, int out_size, void* d_ws, size_t ws_size,
                              hipStream_t stream) {
  (void)in_sizes; (void)n_in; (void)out_size; (void)ws_size;
  const float* x  = (const float*)d_in[0];
  const float* Wq = (const float*)d_in[1];
  const float* Wk = (const float*)d_in[2];
  const float* Wv = (const float*)d_in[3];
  const float* Wo = (const float*)d_in[4];
  const float* bo = (const float*)d_in[5];
  float* out = (float*)d_out;
  char* ws = (char*)d_ws;
  bf16* Xb  = (bf16*)(ws);
  bf16* Wts = (bf16*)(ws + 8388608);
  bf16* Qb  = (bf16*)(ws + 10485760);
  bf16* Kb  = (bf16*)(ws + 18874368);
  bf16* Vtb = (bf16*)(ws + 27262976);
  bf16* Ob  = (bf16*)(ws + 35651584);

  hipLaunchKernelGGL(k_cvt_x, dim3(4096), dim3(256), 0, stream, x, Xb);
  hipLaunchKernelGGL(k_cvt_w, dim3(4096), dim3(256), 0, stream, Wq, Wk, Wv, Wo, Wts);
  hipLaunchKernelGGL(k_gemm_qkv, dim3(64, 4, 3), dim3(256), 0, stream,
                     Xb, Wts, Qb, Kb, Vtb);
  hipLaunchKernelGGL(k_attn, dim3(32, 16), dim3(512), 0, stream, Qb, Kb, Vtb, Ob);
  hipLaunchKernelGGL(k_gemm_out, dim3(64, 4), dim3(256), 0, stream,
                     Ob, Wts + 3 * 262144, bo, out);
}

// Round 5
// 149.907 us; speedup vs baseline: 1.4866x; 1.0408x over previous
//
#include <hip/hip_runtime.h>

// ---------------------------------------------------------------------------
// CrossAttention (self-attn): B=2 N=4096 D=512 H=8 DH=64
// Pipeline: cvt(x,W) -> GEMM qkv (bf16 mfma, V stored transposed) ->
//           flash attention (mfma 32x32x16, KV-split x2 per block, in-register
//           P, packed-f32 softmax, hoisted LDS addressing, LDS combine) ->
//           GEMM out + bias
// Workspace layout (bytes):
//   Xb   @ 0         : 8192x512 bf16   (8,388,608)
//   WtQ/K/V/O @ 8388608 : 4 x 512x512 bf16 (N-major)  (2,097,152)
//   Q    @ 10485760  : (B,H,N,DH) bf16, pre-scaled by SCALE*log2(e)
//   K    @ 18874368  : (B,H,N,DH) bf16
//   Vt   @ 27262976  : (B,H,DH,N) bf16  (transposed for PV B-fragments)
//   O    @ 35651584  : (B,N,H*DH) bf16
// ---------------------------------------------------------------------------

typedef __bf16 bf16;
typedef __bf16 bf16x2 __attribute__((ext_vector_type(2)));
typedef __bf16 bf16x4 __attribute__((ext_vector_type(4)));
typedef __bf16 bf16x8 __attribute__((ext_vector_type(8)));
typedef float  f32x2  __attribute__((ext_vector_type(2)));
typedef float  f32x4  __attribute__((ext_vector_type(4)));
typedef float  f32x16 __attribute__((ext_vector_type(16)));

#define MFMA16 __builtin_amdgcn_mfma_f32_16x16x32_bf16
#define MFMA32 __builtin_amdgcn_mfma_f32_32x32x16_bf16

// XOR swizzle for 128B-row LDS tiles: byte ^= ((row&7)<<4)
__device__ __forceinline__ int swz(int b) { return b ^ ((b >> 3) & 0x70); }

__device__ __forceinline__ void gload16(const void* g, void* l) {
  __builtin_amdgcn_global_load_lds(
      (const __attribute__((address_space(1))) unsigned int*)g,
      (__attribute__((address_space(3))) unsigned int*)l, 16, 0, 0);
}

__device__ __forceinline__ unsigned pk2(float a, float b) {
  union { bf16x2 h; unsigned u; } x;
  x.h[0] = (bf16)a; x.h[1] = (bf16)b;
  return x.u;
}

// ---------------------------------------------------------------------------
// fused convert: blocks [0,4096): x -> bf16 (4 elems/thread)
//                blocks [4096,8192): W^T -> bf16 (1 elem/thread)
__global__ __launch_bounds__(256) void k_cvt(const float* __restrict__ x,
                                             const float* __restrict__ Wq,
                                             const float* __restrict__ Wk,
                                             const float* __restrict__ Wv,
                                             const float* __restrict__ Wo,
                                             bf16* __restrict__ xb,
                                             bf16* __restrict__ Wts) {
  int bid = blockIdx.x;
  if (bid < 4096) {
    int i = (bid * 256 + threadIdx.x) * 4;
    f32x4 v = *(const f32x4*)(x + i);
    bf16x4 o;
    o[0] = (bf16)v[0]; o[1] = (bf16)v[1]; o[2] = (bf16)v[2]; o[3] = (bf16)v[3];
    *(bf16x4*)(xb + i) = o;
  } else {
    int t = (bid - 4096) * 256 + threadIdx.x;   // 0 .. 4*512*512-1
    int w = t >> 18, idx = t & 262143;
    int k = idx >> 9, n = idx & 511;
    const float* W = (w == 0) ? Wq : (w == 1) ? Wk : (w == 2) ? Wv : Wo;
    Wts[(size_t)w * 262144 + n * 512 + k] = (bf16)W[k * 512 + n];
  }
}

// ---------------------------------------------------------------------------
// 128x128 tile GEMM mainloop, K=512, BK=64, 4 waves (2x2 of 64x64)
__device__ __forceinline__ void gemm_mainloop(const char* Ag, const char* Bg,
                                              char* sA, char* sB, f32x4 acc[4][4]) {
  const int tid = threadIdx.x;
  const int g = (tid >> 4) & 3, lr = tid & 15;
  const int wr = ((tid >> 7) & 1) * 64, wc = ((tid >> 6) & 1) * 64;
  f32x4 zero = {0.f, 0.f, 0.f, 0.f};
#pragma unroll
  for (int mt = 0; mt < 4; mt++)
#pragma unroll
    for (int nt = 0; nt < 4; nt++) acc[mt][nt] = zero;

  for (int k0 = 0; k0 < 512; k0 += 64) {
#pragma unroll
    for (int i = 0; i < 4; i++) {  // A tile: 128 rows x 64 k (16KB)
      int c = i * 256 + tid;
      int row = c >> 3, cl = (c & 7) ^ (row & 7);   // pre-swizzled source chunk
      gload16(Ag + row * 1024 + k0 * 2 + cl * 16, sA + (c & ~63) * 16);
    }
#pragma unroll
    for (int i = 0; i < 4; i++) {  // B tile (N-major weights): 128 rows x 64 k
      int c = i * 256 + tid;
      int row = c >> 3, cl = (c & 7) ^ (row & 7);
      gload16(Bg + row * 1024 + k0 * 2 + cl * 16, sB + (c & ~63) * 16);
    }
    __syncthreads();
#pragma unroll
    for (int kk = 0; kk < 2; kk++) {
      bf16x8 af[4], bfr[4];
#pragma unroll
      for (int mt = 0; mt < 4; mt++)
        af[mt] = *(const bf16x8*)(sA + swz((wr + mt * 16 + lr) * 128 + kk * 64 + g * 16));
#pragma unroll
      for (int nt = 0; nt < 4; nt++)
        bfr[nt] = *(const bf16x8*)(sB + swz((wc + nt * 16 + lr) * 128 + kk * 64 + g * 16));
#pragma unroll
      for (int mt = 0; mt < 4; mt++)
#pragma unroll
        for (int nt = 0; nt < 4; nt++)
          acc[mt][nt] = MFMA16(af[mt], bfr[nt], acc[mt][nt], 0, 0, 0);
    }
    __syncthreads();
  }
}

// z = 0:Q (scaled), 1:K, 2:V (transposed store)
__global__ __launch_bounds__(256) void k_gemm_qkv(const bf16* __restrict__ Xb,
                                                  const bf16* __restrict__ Wts,
                                                  bf16* __restrict__ Qo,
                                                  bf16* __restrict__ Ko,
                                                  bf16* __restrict__ Vto) {
  __shared__ __align__(16) char smem[32768];
  const int tid = threadIdx.x;
  const int g = (tid >> 4) & 3, lr = tid & 15;
  const int mb = blockIdx.x * 128, nb = blockIdx.y * 128;
  const int mode = blockIdx.z;
  f32x4 acc[4][4];
  gemm_mainloop((const char*)Xb + (size_t)mb * 1024,
                (const char*)(Wts + (size_t)mode * 262144) + (size_t)nb * 1024,
                smem, smem + 16384, acc);
  const int wr = ((tid >> 7) & 1) * 64, wc = ((tid >> 6) & 1) * 64;
  const float qs = 0.18033688011112042f;  // DH^-0.5 * log2(e)
#pragma unroll
  for (int mt = 0; mt < 4; mt++)
#pragma unroll
    for (int nt = 0; nt < 4; nt++)
#pragma unroll
      for (int r = 0; r < 4; r++) {
        int m = mb + wr + mt * 16 + g * 4 + r;       // global row (b*4096+n)
        int cc = nb + wc + nt * 16 + lr;             // col (h*64+d)
        float v = acc[mt][nt][r];
        int b = m >> 12, ns = m & 4095, h = cc >> 6, d = cc & 63;
        if (mode == 0)
          Qo[((size_t)(b * 8 + h) * 4096 + ns) * 64 + d] = (bf16)(v * qs);
        else if (mode == 1)
          Ko[((size_t)(b * 8 + h) * 4096 + ns) * 64 + d] = (bf16)v;
        else
          Vto[((size_t)(b * 8 + h) * 64 + d) * 4096 + ns] = (bf16)v;
      }
}

__global__ __launch_bounds__(256) void k_gemm_out(const bf16* __restrict__ Ob,
                                                  const bf16* __restrict__ WtO,
                                                  const float* __restrict__ bo,
                                                  float* __restrict__ out) {
  __shared__ __align__(16) char smem[32768];
  const int tid = threadIdx.x;
  const int g = (tid >> 4) & 3, lr = tid & 15;
  const int mb = blockIdx.x * 128, nb = blockIdx.y * 128;
  f32x4 acc[4][4];
  gemm_mainloop((const char*)Ob + (size_t)mb * 1024,
                (const char*)WtO + (size_t)nb * 1024, smem, smem + 16384, acc);
  const int wr = ((tid >> 7) & 1) * 64, wc = ((tid >> 6) & 1) * 64;
#pragma unroll
  for (int mt = 0; mt < 4; mt++)
#pragma unroll
    for (int nt = 0; nt < 4; nt++)
#pragma unroll
      for (int r = 0; r < 4; r++) {
        int m = mb + wr + mt * 16 + g * 4 + r;
        int cc = nb + wc + nt * 16 + lr;
        out[(size_t)m * 512 + cc] = acc[mt][nt][r] + bo[cc];
      }
}

// ---------------------------------------------------------------------------
// Flash attention, 32x32x16 MFMA. Block = 512 threads = 8 warps:
//   warp w: q-strip (w&3)*32, KV-half (w>>2). Each half loops 32 tiles of 64.
//   Warp pairs (w, w^4) combine partial (m, l, acc) through LDS at the end.
// LDS per half: dbuf x (K 8K @rows 0..63 | V 8K @+8192).
// All 16 per-tile ds_reads derive from ONE hoisted swizzled base:
//   swz(lo*128 + ks*32 + hi*16) == swz(lo*128 + hi*16) ^ (ks*32)
//   row+32 -> +4096 bytes (swizzle mask uses row&7, unchanged).
__global__ __launch_bounds__(512, 4) void k_attn(const bf16* __restrict__ Q,
                                                 const bf16* __restrict__ K,
                                                 const bf16* __restrict__ Vt,
                                                 bf16* __restrict__ O) {
  __shared__ __align__(16) char smem[65536];  // 2 halves x dbuf x (K 8K | V 8K)
  const int tid = threadIdx.x;
  const int l = tid & 63, w = tid >> 6, lo = l & 31, hi = l >> 5;
  const int strip = w & 3, half = w >> 2;
  const int tid2 = tid & 255;
  const int bh = blockIdx.y;                       // b*8+h
  const int q0 = blockIdx.x * 128 + strip * 32;    // warp's q strip
  // Q B-fragments: qf[ks] = Q[q0+lo][ks*16 + hi*8 .. +7] (Q pre-scaled)
  const char* Qp = (const char*)Q + ((size_t)bh * 4096 + q0 + lo) * 128;
  bf16x8 qf[4];
#pragma unroll
  for (int ks = 0; ks < 4; ks++) qf[ks] = *(const bf16x8*)(Qp + ks * 32 + hi * 16);

  // ---- staging pointers (incremental; half's 256 threads stage its buffers)
  const int srow = tid2 >> 3, scl = (tid2 & 7) ^ (srow & 7);
  const char* pK0 = (const char*)K + (size_t)bh * 4096 * 128 +
                    (size_t)half * 2048 * 128 + srow * 128 + scl * 16;
  const char* pV0 = (const char*)Vt + (size_t)bh * 64 * 8192 +
                    (size_t)half * 4096 + (size_t)srow * 8192 + scl * 16;
  char* lbase = smem + half * 32768;
  const int sdst = (tid2 & ~63) * 16;              // wave-uniform LDS dst base

  // ---- hoisted per-lane LDS read base (relative to current buffer)
  const int offR = swz(lo * 128 + hi * 16);

  f32x16 acc0 = {0.f}, acc1 = {0.f};
  float mrun = -3.0e38f, lsum = 0.f;

  // prologue: stage tile 0 into buffer 0
  {
    char* d = lbase + sdst;
    gload16(pK0, d);                    // K rows 0..31
    gload16(pK0 + 4096, d + 4096);      // K rows 32..63
    gload16(pV0, d + 8192);             // V d-rows 0..31
    gload16(pV0 + 262144, d + 12288);   // V d-rows 32..63
  }
  pK0 += 8192; pV0 += 128;
  __syncthreads();

  for (int t = 0; t < 32; t++) {
    if (t < 31) {  // async prefetch t+1 into other buffer
      char* d = lbase + ((t + 1) & 1) * 16384 + sdst;
      gload16(pK0, d);
      gload16(pK0 + 4096, d + 4096);
      gload16(pV0, d + 8192);
      gload16(pV0 + 262144, d + 12288);
      pK0 += 8192; pV0 += 128;
    }
    const char* b0 = lbase + (t & 1) * 16384;
    const char* pk_[4] = {b0 + offR, b0 + (offR ^ 32), b0 + (offR ^ 64),
                          b0 + (offR ^ 96)};
    // ---- QK^T: S^T[kv 64][q 32], two 32-kv chunks
    f32x16 s0v = {0.f}, s1v = {0.f};
    __builtin_amdgcn_s_setprio(1);
#pragma unroll
    for (int ks = 0; ks < 4; ks++) {
      bf16x8 kf0 = *(const bf16x8*)(pk_[ks]);
      bf16x8 kf1 = *(const bf16x8*)(pk_[ks] + 4096);
      s0v = MFMA32(kf0, qf[ks], s0v, 0, 0, 0);
      s1v = MFMA32(kf1, qf[ks], s1v, 0, 0, 0);
    }
    __builtin_amdgcn_s_setprio(0);
    union C16 { f32x16 v; f32x2 d[8]; float f[16]; };
    C16 S0, S1; S0.v = s0v; S1.v = s1v;
    // ---- row max (own q = lo): packed-f32 tree
    f32x2 t8[8];
#pragma unroll
    for (int r = 0; r < 8; r++) t8[r] = __builtin_elementwise_max(S0.d[r], S1.d[r]);
#pragma unroll
    for (int r = 0; r < 4; r++) t8[r] = __builtin_elementwise_max(t8[r], t8[r + 4]);
    t8[0] = __builtin_elementwise_max(t8[0], t8[2]);
    t8[1] = __builtin_elementwise_max(t8[1], t8[3]);
    t8[0] = __builtin_elementwise_max(t8[0], t8[1]);
    float pmax = fmaxf(t8[0][0], t8[0][1]);
    pmax = fmaxf(pmax, __shfl_xor(pmax, 32, 64));
    // ---- defer-max (THR=8 in log2 domain)
    if (t == 0) {
      mrun = pmax;
    } else if (!__all(pmax - mrun <= 8.0f)) {
      float mnew = fmaxf(mrun, pmax);
      float alpha = __builtin_amdgcn_exp2f(mrun - mnew);
      lsum *= alpha;
#pragma unroll
      for (int r = 0; r < 16; r++) {
        float af = __shfl(alpha, (r & 3) + 8 * (r >> 2) + 4 * hi, 64);
        acc0[r] *= af; acc1[r] *= af;
      }
      mrun = mnew;
    }
    // ---- p = exp2(s - m) (packed subtract, scalar exp)
    const f32x2 mb2 = {mrun, mrun};
#pragma unroll
    for (int r = 0; r < 8; r++) { S0.d[r] -= mb2; S1.d[r] -= mb2; }
#pragma unroll
    for (int r = 0; r < 16; r++) {
      S0.f[r] = __builtin_amdgcn_exp2f(S0.f[r]);
      S1.f[r] = __builtin_amdgcn_exp2f(S1.f[r]);
    }
    // ---- row sum: packed tree
    f32x2 sa[8];
#pragma unroll
    for (int r = 0; r < 8; r++) sa[r] = S0.d[r] + S1.d[r];
#pragma unroll
    for (int r = 0; r < 4; r++) sa[r] += sa[r + 4];
    sa[0] += sa[2]; sa[1] += sa[3]; sa[0] += sa[1];
    float rs = sa[0][0] + sa[0][1];
    rs += __shfl_xor(rs, 32, 64);
    lsum += rs;
    // ---- pack P into A-fragments: cvt_pk + permlane32_swap (T12)
    union U8 { unsigned u[4]; bf16x8 v; };
    bf16x8 pa[4];
#pragma unroll
    for (int j = 0; j < 4; j++) {
      const float* sp = (j < 2) ? S0.f : S1.f;
      int base = (j & 1) * 8;
      unsigned A0 = pk2(sp[base + 0], sp[base + 1]), A1 = pk2(sp[base + 2], sp[base + 3]);
      unsigned B0 = pk2(sp[base + 4], sp[base + 5]), B1 = pk2(sp[base + 6], sp[base + 7]);
      asm("v_permlane32_swap_b32 %0, %1" : "+v"(A0), "+v"(B0));
      asm("v_permlane32_swap_b32 %0, %1" : "+v"(A1), "+v"(B1));
      U8 pu;
      pu.u[0] = A0; pu.u[1] = A1; pu.u[2] = B0; pu.u[3] = B1;
      pa[j] = pu.v;
    }
    // ---- PV: O[32q][64d] += P[32q][64kv] V[64kv][64d]
    __builtin_amdgcn_s_setprio(1);
#pragma unroll
    for (int ks = 0; ks < 4; ks++) {
      bf16x8 vf0 = *(const bf16x8*)(pk_[ks] + 8192);
      bf16x8 vf1 = *(const bf16x8*)(pk_[ks] + 12288);
      acc0 = MFMA32(pa[ks], vf0, acc0, 0, 0, 0);
      acc1 = MFMA32(pa[ks], vf1, acc1, 0, 0, 0);
    }
    __builtin_amdgcn_s_setprio(0);
    __syncthreads();
  }
  // ---- combine halves via LDS (warp pairs w <-> w^4), then write O
  float* accStash = (float*)smem;            // [4 strips][32 q][64 d] f32 = 32KB
  float* mArr = (float*)(smem + 32768);      // [8 warps][32 q]
  float* lArr = (float*)(smem + 36864);      // [8 warps][32 q]
  float* cArr = (float*)(smem + 40960);      // [8 warps][32 q]: exp2(m-mn)/ln
  if (l < 32) { mArr[w * 32 + lo] = mrun; lArr[w * 32 + lo] = lsum; }
  __syncthreads();
  if (l < 32) {
    float mP = mArr[(w ^ 4) * 32 + lo];
    float lP = lArr[(w ^ 4) * 32 + lo];
    float mn = fmaxf(mrun, mP);
    float wS = __builtin_amdgcn_exp2f(mrun - mn);
    float wP = __builtin_amdgcn_exp2f(mP - mn);
    cArr[w * 32 + lo] = wS / (lsum * wS + lP * wP);
  }
  __syncthreads();
  if (half == 1) {  // stash scaled partial
#pragma unroll
    for (int r = 0; r < 16; r++) {
      int qrow = (r & 3) + 8 * (r >> 2) + 4 * hi;
      float cf = cArr[w * 32 + qrow];
      accStash[(strip * 32 + qrow) * 64 + lo] = acc0[r] * cf;
      accStash[(strip * 32 + qrow) * 64 + lo + 32] = acc1[r] * cf;
    }
  }
  __syncthreads();
  if (half == 0) {  // merge + write O (B, N, H*64) bf16
    const int b = bh >> 3, h = bh & 7;
#pragma unroll
    for (int r = 0; r < 16; r++) {
      int qrow = (r & 3) + 8 * (r >> 2) + 4 * hi;
      float cf = cArr[w * 32 + qrow];
      float o0 = acc0[r] * cf + accStash[(strip * 32 + qrow) * 64 + lo];
      float o1 = acc1[r] * cf + accStash[(strip * 32 + qrow) * 64 + lo + 32];
      size_t base = ((size_t)b * 4096 + q0 + qrow) * 512 + h * 64 + lo;
      O[base] = (bf16)o0;
      O[base + 32] = (bf16)o1;
    }
  }
}

// ---------------------------------------------------------------------------
extern "C" void kernel_launch(void* const* d_in, const int* in_sizes, int n_in,
                              void* d_out, int out_size, void* d_ws, size_t ws_size,
                              hipStream_t stream) {
  (void)in_sizes; (void)n_in; (void)out_size; (void)ws_size;
  const float* x  = (const float*)d_in[0];
  const float* Wq = (const float*)d_in[1];
  const float* Wk = (const float*)d_in[2];
  const float* Wv = (const float*)d_in[3];
  const float* Wo = (const float*)d_in[4];
  const float* bo = (const float*)d_in[5];
  float* out = (float*)d_out;
  char* ws = (char*)d_ws;
  bf16* Xb  = (bf16*)(ws);
  bf16* Wts = (bf16*)(ws + 8388608);
  bf16* Qb  = (bf16*)(ws + 10485760);
  bf16* Kb  = (bf16*)(ws + 18874368);
  bf16* Vtb = (bf16*)(ws + 27262976);
  bf16* Ob  = (bf16*)(ws + 35651584);

  hipLaunchKernelGGL(k_cvt, dim3(8192), dim3(256), 0, stream,
                     x, Wq, Wk, Wv, Wo, Xb, Wts);
  hipLaunchKernelGGL(k_gemm_qkv, dim3(64, 4, 3), dim3(256), 0, stream,
                     Xb, Wts, Qb, Kb, Vtb);
  hipLaunchKernelGGL(k_attn, dim3(32, 16), dim3(512), 0, stream, Qb, Kb, Vtb, Ob);
  hipLaunchKernelGGL(k_gemm_out, dim3(64, 4), dim3(256), 0, stream,
                     Ob, Wts + 3 * 262144, bo, out);
}